// Round 20
// baseline (192.062 us; speedup 1.0000x reference)
//
#include <hip/hip_runtime.h>
#include <hip/hip_cooperative_groups.h>
namespace cg = cooperative_groups;

#define NB 32
#define NL 1024
#define NC 64
#define NO 64
constexpr float BN_EPS = 1e-5f;

// ws layout (float units):
//  [128..32895]   d  (B*L row degrees)  at D_OFF
//  [32896..49279] bn partials (128 blocks x 64 ch, sum then sumsq)
//  [131072..]     Yt tiled bf16: [b][kt] 8KB tiles, swizzled   (4 MB)
#define D_OFF 128
#define PART_OFF 32896
#define YT_OFF 131072      // byte 512 KB

typedef short          s16x8 __attribute__((ext_vector_type(8)));
typedef float          f32x16 __attribute__((ext_vector_type(16)));
typedef float          f32x4  __attribute__((ext_vector_type(4)));

__device__ inline unsigned short f2bf(float f) {
    union { float f; unsigned u; } v; v.f = f;
    unsigned u = v.u + 0x7FFFu + ((v.u >> 16) & 1u);   // round-to-nearest-even
    return (unsigned short)(u >> 16);
}

__device__ inline void gload16(const void* g, void* l) {
    __builtin_amdgcn_global_load_lds(
        (const __attribute__((address_space(1))) unsigned int*)g,
        (__attribute__((address_space(3))) unsigned int*)l, 16, 0, 0);
}

// fp32x8 -> bf16x8 via packed cvt (RNE on gfx950)
__device__ inline s16x8 cvt8(f32x4 lo, f32x4 hi) {
    union { unsigned int i[4]; s16x8 v; } u;
    asm("v_cvt_pk_bf16_f32 %0, %1, %2" : "=v"(u.i[0]) : "v"(lo.x), "v"(lo.y));
    asm("v_cvt_pk_bf16_f32 %0, %1, %2" : "=v"(u.i[1]) : "v"(lo.z), "v"(lo.w));
    asm("v_cvt_pk_bf16_f32 %0, %1, %2" : "=v"(u.i[2]) : "v"(hi.x), "v"(hi.y));
    asm("v_cvt_pk_bf16_f32 %0, %1, %2" : "=v"(u.i[3]) : "v"(hi.z), "v"(hi.w));
    return u.v;
}

// ============ fused cooperative kernel: 512 blocks x 256 threads =============
// Phase 1: deg (64 own A-rows, 3-buf counted-vmcnt pipeline) + BN partials
// Phase 2: X = Hn@W+b via MFMA (BN folded into W'), Yt tiles
// Phase 3: out = leaky(X - sqrt(d_i) * A@Y) via MFMA
__global__ __launch_bounds__(256) void gcn_fused(
    const float* __restrict__ A, const float* __restrict__ H,
    const float* __restrict__ Wm, const float* __restrict__ bias,
    const float* __restrict__ gamma, const float* __restrict__ beta,
    float* __restrict__ ws, float* __restrict__ X,
    unsigned short* __restrict__ Yt) {

    __shared__ __align__(16) char smem[52480];
    const int blk = blockIdx.x;
    const int t = threadIdx.x, lane = t & 63, w = t >> 6;

    // ---------------- Phase 1: degrees (rows blk*64 .. +64) ------------------
    {
        const size_t row0 = (size_t)blk * 64;
        const char* src = (const char*)A + row0 * 4096;        // 256 KB in
        const int lo = w * 4096 + lane * 16;   // wave-own region (4 KB of chunk)
#define STG(bi, c) do {                                                        \
            char* d0 = smem + (bi) * 16384 + lo;                               \
            const char* s0 = src + (c) * 16384 + lo;                           \
            gload16(s0,        d0);                                            \
            gload16(s0 + 1024, d0 + 1024);                                     \
            gload16(s0 + 2048, d0 + 2048);                                     \
            gload16(s0 + 3072, d0 + 3072);                                     \
        } while (0)
        STG(0, 0); STG(1, 1); STG(2, 2);     // 3 chunks (12 loads/wave) in flight
        int cb = 0;
#pragma unroll 1
        for (int c = 0; c < 16; ++c) {
            if (c <= 13)     asm volatile("s_waitcnt vmcnt(8)" ::: "memory");
            else if (c == 14) asm volatile("s_waitcnt vmcnt(4)" ::: "memory");
            else             asm volatile("s_waitcnt vmcnt(0)" ::: "memory");
            __builtin_amdgcn_sched_barrier(0);
            const char* cbp = smem + cb * 16384 + lo;
            float s = 0.f;
#pragma unroll
            for (int j = 0; j < 4; ++j) {
                f32x4 v = *(const f32x4*)(cbp + j * 1024);
                s += v.x + v.y + v.z + v.w;
            }
#pragma unroll
            for (int m = 32; m; m >>= 1) s += __shfl_xor(s, m, 64);
            if (lane == 0) ws[D_OFF + row0 + c * 4 + w] = s;   // wave owns the row
            __builtin_amdgcn_sched_barrier(0);   // keep restage below the reads
            if (c + 3 < 16) STG(cb, c + 3);      // overwrite wave-own freed region
            cb = (cb == 2) ? 0 : cb + 1;
        }
#undef STG
    }
    // BN partial sums: blocks 0..127, 256 H-rows each (after deg: vmcnt drained)
    if (blk < 128) {
        __syncthreads();                          // deg LDS reads done, reuse smem
        float* part = (float*)smem;               // [256][8]
        const float4* Hv = (const float4*)H + blk * 4096;
        float s0 = 0.f, s1 = 0.f, s2 = 0.f, s3 = 0.f;
        float q0 = 0.f, q1 = 0.f, q2 = 0.f, q3 = 0.f;
#pragma unroll 4
        for (int s = 0; s < 16; ++s) {
            float4 v = Hv[s * 256 + t];
            s0 += v.x; q0 += v.x * v.x;
            s1 += v.y; q1 += v.y * v.y;
            s2 += v.z; q2 += v.z * v.z;
            s3 += v.w; q3 += v.w * v.w;
        }
        part[t * 8 + 0] = s0; part[t * 8 + 1] = s1;
        part[t * 8 + 2] = s2; part[t * 8 + 3] = s3;
        part[t * 8 + 4] = q0; part[t * 8 + 5] = q1;
        part[t * 8 + 6] = q2; part[t * 8 + 7] = q3;
        __syncthreads();
        if (t < 64) {
            const int g = t >> 2, e = t & 3;
            float a = 0.f, a2 = 0.f;
#pragma unroll
            for (int k = 0; k < 16; ++k) {
                a  += part[(g + 16 * k) * 8 + e];
                a2 += part[(g + 16 * k) * 8 + 4 + e];
            }
            ws[PART_OFF + blk * 64 + t] = a;
            ws[PART_OFF + 128 * 64 + blk * 64 + t] = a2;
        }
    }

    cg::this_grid().sync();

    // ---------------- Phase 2: linear (b = blk>>4, ch = blk&15) --------------
    {
        float* Hl            = (float*)(smem);                   // 16 KB
        float* Wl            = (float*)(smem + 16384);           // 16 KB
        unsigned short* Wbf  = (unsigned short*)(smem + 32768);  // 8 KB
        typedef unsigned short ytrow[66];
        ytrow* ytile         = (ytrow*)(smem + 40960);           // 8448 B
        float* ls            = (float*)(smem + 49408);           // 1 KB
        float* ls2           = (float*)(smem + 50432);           // 1 KB
        float* sscale        = (float*)(smem + 51456);
        float* sshift        = (float*)(smem + 51712);
        float* bp            = (float*)(smem + 51968);
        float* sdl           = (float*)(smem + 52224);
        const int b = blk >> 4, ch = blk & 15;
        const int r0g = b * NL + ch * 64;

        // 1. async H staging: 64 rows x 256B, source-side inverse swizzle
        {
            const char* hsrc = (const char*)H + (size_t)r0g * 256;
#pragma unroll
            for (int i = 0; i < 4; ++i) {
                const int L = i * 4096 + t * 16;
                const int row = L >> 8, cb2 = L & 255;
                gload16(hsrc + (size_t)row * 256 + (cb2 ^ ((row & 7) << 4)),
                        (char*)Hl + L);
            }
        }
        // 2. W load + sdl preload + BN partial reduce (overlap H latency)
        {
            const float4* Wv = (const float4*)Wm;
            float4* Wd = (float4*)Wl;
#pragma unroll
            for (int k = 0; k < 4; ++k) Wd[t + k * 256] = Wv[t + k * 256];
        }
        if (t < 64) sdl[t] = rsqrtf(ws[D_OFF + r0g + t]);
        {
            const float* ps  = ws + PART_OFF;
            const float* ps2 = ws + PART_OFF + 128 * 64;
            const int c = t & 63, q = t >> 6;
            float s = 0.f, s2 = 0.f;
            for (int p = q * 32; p < q * 32 + 32; ++p) {
                s  += ps[p * 64 + c];
                s2 += ps2[p * 64 + c];
            }
            ls[t] = s; ls2[t] = s2;
        }
        __syncthreads();
        if (t < 64) {
            const int c = t;
            float T  = ls[c]  + ls[c + 64]  + ls[c + 128]  + ls[c + 192];
            float T2 = ls2[c] + ls2[c + 64] + ls2[c + 128] + ls2[c + 192];
            const float n = (float)(NB * NL);
            float mean = T / n;
            float var  = T2 / n - mean * mean;
            float sc = gamma[c] * rsqrtf(var + BN_EPS);
            sscale[c] = sc;
            sshift[c] = beta[c] - mean * sc;
        }
        __syncthreads();
        // 3. b' partials
        {
            float p = 0.f;
#pragma unroll
            for (int c0 = 0; c0 < 16; ++c0) {
                const int c = w * 16 + c0;
                p += sshift[c] * Wl[c * 64 + lane];
            }
            ls[t] = p;
        }
        // 4. W' bf16 [o][c] swizzled
#pragma unroll
        for (int c0 = 0; c0 < 16; ++c0) {
            const int c = w * 16 + c0;
            const float v = sscale[c] * Wl[c * 64 + lane];
            *(unsigned short*)((char*)Wbf +
                ((lane * 128 + c * 2) ^ ((lane & 7) << 4))) = f2bf(v);
        }
        __syncthreads();             // ls/Wbf ready, vmcnt drained (Hl resident)
        if (t < 64) bp[t] = bias[t] + ls[t] + ls[t + 64] + ls[t + 128] + ls[t + 192];
        __syncthreads();

        // 5. MFMA 4 waves x 32x32
        const int wr0  = (w >> 1) * 32;
        const int wc0  = (w & 1) * 32;
        const int frow = wr0 + (lane & 31);
        const int fcol = wc0 + (lane & 31);
        const int khb  = (lane >> 5) * 16;
        const int kfh  = (lane >> 5) * 32;
        const int swA  = (frow & 7) << 4;
        const int swY  = (fcol & 7) << 4;
        f32x16 acc;
#pragma unroll
        for (int r = 0; r < 16; ++r) acc[r] = 0.f;
        const char* ab = (const char*)Hl;
        const char* wb = (const char*)Wbf;
#pragma unroll
        for (int ks = 0; ks < 4; ++ks) {
            const int b0 = frow * 256 + ks * 64 + kfh;
            f32x4 flo = *(const f32x4*)(ab + ((b0)      ^ swA));
            f32x4 fhi = *(const f32x4*)(ab + ((b0 + 16) ^ swA));
            s16x8 af = cvt8(flo, fhi);
            s16x8 bf = *(const s16x8*)(wb + ((fcol * 128 + ks * 32 + khb) ^ swY));
            acc = __builtin_amdgcn_mfma_f32_32x32x16_bf16(af, bf, acc, 0, 0, 0);
        }
        // 6. epilogue: X, ytile
#pragma unroll
        for (int reg = 0; reg < 16; ++reg) {
            const int row = wr0 + (reg & 3) + 8 * (reg >> 2) + 4 * (lane >> 5);
            const int col = wc0 + (lane & 31);
            const float x = acc[reg] + bp[col];
            X[(size_t)(r0g + row) * NO + col] = x;
            ytile[row][col] = f2bf(x * sdl[row]);
        }
        __syncthreads();
        // 7. coalesced swizzled Yt tile write
        char* ybase = (char*)Yt + (size_t)(b * 16 + ch) * 8192;
#pragma unroll
        for (int i2 = 0; i2 < 16; ++i2) {
            const int col = i2 * 4 + w;
            *(unsigned short*)(ybase +
                ((col * 128 + lane * 2) ^ ((col & 7) << 4))) = ytile[lane][col];
        }
    }

    cg::this_grid().sync();

    // ---------------- Phase 3: prop (b = blk>>4, mt = blk&15) ----------------
    {
        char* Ab0 = smem;                         // 16 KB fp32 (swizzled)
        char* Ab1 = smem + 16384;                 // 16 KB
        char* Yb0 = smem + 32768;                 // 8 KB bf16
        char* Yb1 = smem + 40960;                 // 8 KB
        float* sdl = (float*)(smem + 49152);      // 256 B

        const int b  = blk >> 4;
        const int mt = blk & 15;
        const int i0 = mt * 64;
        const char* Abase = (const char*)A + ((size_t)(b * NL + i0)) * 4096;
        const char* YbT   = (const char*)Yt + (size_t)b * 16 * 8192;

        if (t < 64) sdl[t] = sqrtf(ws[D_OFF + b * NL + i0 + t]);

        const int tr = t >> 4;
        const int tc = (t & 15) * 16;
        const char* As[4];
#pragma unroll
        for (int i = 0; i < 4; ++i) {
            const int row = i * 16 + tr;
            As[i] = Abase + (size_t)row * 4096 + (tc ^ ((row & 7) << 4));
        }
        const int yL0 = t * 16, yL1 = t * 16 + 4096;

        const int wr0  = (w >> 1) * 32;
        const int wc0  = (w & 1) * 32;
        const int frow = wr0 + (lane & 31);
        const int fcol = wc0 + (lane & 31);
        const int khb  = (lane >> 5) * 16;
        const int kfh  = (lane >> 5) * 32;
        const int swA  = (frow & 7) << 4;
        const int swY  = (fcol & 7) << 4;

        f32x16 acc;
#pragma unroll
        for (int r = 0; r < 16; ++r) acc[r] = 0.f;

#define STAGE(bi, kt) do {                                                     \
            char* ad = (bi) ? Ab1 : Ab0;                                       \
            gload16(As[0] + (kt) * 256, ad + t * 16);                          \
            gload16(As[1] + (kt) * 256, ad + 4096  + t * 16);                  \
            gload16(As[2] + (kt) * 256, ad + 8192  + t * 16);                  \
            gload16(As[3] + (kt) * 256, ad + 12288 + t * 16);                  \
            const char* ys = YbT + (size_t)(kt) * 8192;                        \
            char* yd = (bi) ? Yb1 : Yb0;                                       \
            gload16(ys + yL0, yd + yL0);                                       \
            gload16(ys + yL1, yd + yL1);                                       \
        } while (0)

        STAGE(0, 0);
        __syncthreads();

#pragma unroll 1
        for (int kti = 0; kti < 16; ++kti) {
            const int nxt = kti + 1;
            if (nxt < 16) STAGE(nxt & 1, nxt);      // prefetch next tile (async)
            const char* ab  = (kti & 1) ? Ab1 : Ab0;
            const char* yb2 = (kti & 1) ? Yb1 : Yb0;
#pragma unroll
            for (int ks = 0; ks < 4; ++ks) {
                const int b0 = frow * 256 + ks * 64 + kfh;
                f32x4 flo = *(const f32x4*)(ab + ((b0)      ^ swA));
                f32x4 fhi = *(const f32x4*)(ab + ((b0 + 16) ^ swA));
                s16x8 af = cvt8(flo, fhi);
                s16x8 bf = *(const s16x8*)(yb2 +
                               ((fcol * 128 + ks * 32 + khb) ^ swY));
                acc = __builtin_amdgcn_mfma_f32_32x32x16_bf16(af, bf, acc, 0, 0, 0);
            }
            __syncthreads();                        // next tile resident
        }
#undef STAGE

        // epilogue: out = leaky(X - sqrt(d_i) * acc)
#pragma unroll
        for (int reg = 0; reg < 16; ++reg) {
            int row = (reg & 3) + 8 * (reg >> 2) + 4 * (lane >> 5);
            int i   = i0 + wr0 + row;
            int col = wc0 + (lane & 31);
            size_t idx = ((size_t)(b * NL + i)) * NO + col;
            float x = X[idx];
            float v = x - sdl[wr0 + row] * acc[reg];
            X[idx] = v > 0.f ? v : 0.01f * v;
        }
    }
}

extern "C" void kernel_launch(void* const* d_in, const int* in_sizes, int n_in,
                              void* d_out, int out_size, void* d_ws, size_t ws_size,
                              hipStream_t stream) {
    const float* H     = (const float*)d_in[0];
    const float* A     = (const float*)d_in[1];
    const float* gamma = (const float*)d_in[2];
    const float* beta  = (const float*)d_in[3];
    const float* Wm    = (const float*)d_in[4];
    const float* bias  = (const float*)d_in[5];
    float* out = (float*)d_out;
    float* ws  = (float*)d_ws;
    unsigned short* Yt = (unsigned short*)(ws + YT_OFF);

    void* args[] = {(void*)&A, (void*)&H, (void*)&Wm, (void*)&bias,
                    (void*)&gamma, (void*)&beta, (void*)&ws, (void*)&out,
                    (void*)&Yt};
    hipLaunchCooperativeKernel((void*)gcn_fused, dim3(512), dim3(256),
                               args, 0, stream);
}

// Round 21
// 60.992 us; speedup vs baseline: 3.1489x; 3.1489x over previous
//
#include <hip/hip_runtime.h>

#define NB 32
#define NL 1024
#define NC 64
#define NO 64
constexpr float BN_EPS = 1e-5f;

// ws layout (float units):
//  [128..32895]   d  (B*L row degrees)  at D_OFF
//  [32896..49279] bn partials (128 blocks x 64 ch, sum then sumsq)
//  [131072..]     Yt tiled bf16: [b][kt] 8KB tiles, swizzled   (4 MB)
#define D_OFF 128
#define PART_OFF 32896
#define YT_OFF 131072      // byte 512 KB

typedef short          s16x8 __attribute__((ext_vector_type(8)));
typedef float          f32x16 __attribute__((ext_vector_type(16)));
typedef float          f32x4  __attribute__((ext_vector_type(4)));

__device__ inline unsigned short f2bf(float f) {
    union { float f; unsigned u; } v; v.f = f;
    unsigned u = v.u + 0x7FFFu + ((v.u >> 16) & 1u);   // round-to-nearest-even
    return (unsigned short)(u >> 16);
}

__device__ inline void gload16(const void* g, void* l) {
    __builtin_amdgcn_global_load_lds(
        (const __attribute__((address_space(1))) unsigned int*)g,
        (__attribute__((address_space(3))) unsigned int*)l, 16, 0, 0);
}

// fp32x8 -> bf16x8 via packed cvt (RNE on gfx950)
__device__ inline s16x8 cvt8(f32x4 lo, f32x4 hi) {
    union { unsigned int i[4]; s16x8 v; } u;
    asm("v_cvt_pk_bf16_f32 %0, %1, %2" : "=v"(u.i[0]) : "v"(lo.x), "v"(lo.y));
    asm("v_cvt_pk_bf16_f32 %0, %1, %2" : "=v"(u.i[1]) : "v"(lo.z), "v"(lo.w));
    asm("v_cvt_pk_bf16_f32 %0, %1, %2" : "=v"(u.i[2]) : "v"(hi.x), "v"(hi.y));
    asm("v_cvt_pk_bf16_f32 %0, %1, %2" : "=v"(u.i[3]) : "v"(hi.z), "v"(hi.w));
    return u.v;
}

// ---- Kernel 1: (blocks 0..1023: A row degrees — per-wave 3-deep gload_lds
//                 pipeline, counted vmcnt, NO barriers)
//                (blocks 1024..1151: BN partial sums over H, float4) ----------
__global__ __launch_bounds__(256) void deg_bn(
    const float* __restrict__ A, const float* __restrict__ H,
    float* __restrict__ ws) {
    __shared__ f32x4 smem4[3072];            // 48 KB: 3 x 16KB chunk buffers
    const int t = threadIdx.x;
    if (blockIdx.x < 1024) {
        const int lane = t & 63, w = t >> 6;
        const size_t row0 = (size_t)blockIdx.x * 32;           // 32 A-rows/block
        const char* src = (const char*)A + row0 * 4096;        // 128 KB in
        const int lo = w * 4096 + lane * 16;   // wave-own region (4 KB of chunk)
#define STG(bi, c) do {                                                        \
            char* d0 = (char*)smem4 + (bi) * 16384 + lo;                       \
            const char* s0 = src + (c) * 16384 + lo;                           \
            gload16(s0,        d0);                                            \
            gload16(s0 + 1024, d0 + 1024);                                     \
            gload16(s0 + 2048, d0 + 2048);                                     \
            gload16(s0 + 3072, d0 + 3072);                                     \
        } while (0)
        STG(0, 0); STG(1, 1); STG(2, 2);     // 3 chunks (12 loads/wave) in flight
        int cb = 0;
#pragma unroll 1
        for (int c = 0; c < 8; ++c) {
            if (c <= 5)      asm volatile("s_waitcnt vmcnt(8)" ::: "memory");
            else if (c == 6) asm volatile("s_waitcnt vmcnt(4)" ::: "memory");
            else             asm volatile("s_waitcnt vmcnt(0)" ::: "memory");
            __builtin_amdgcn_sched_barrier(0);
            const char* cbp = (const char*)smem4 + cb * 16384 + lo;
            float s = 0.f;
#pragma unroll
            for (int j = 0; j < 4; ++j) {
                f32x4 v = *(const f32x4*)(cbp + j * 1024);
                s += v.x + v.y + v.z + v.w;
            }
#pragma unroll
            for (int m = 32; m; m >>= 1) s += __shfl_xor(s, m, 64);
            if (lane == 0) ws[D_OFF + row0 + c * 4 + w] = s;   // wave owns the row
            __builtin_amdgcn_sched_barrier(0);   // keep restage below the reads
            if (c + 3 < 8) STG(cb, c + 3);       // overwrite wave-own freed region
            cb = (cb == 2) ? 0 : cb + 1;
        }
#undef STG
    } else {
        // BN stats: block covers 256 rows (4096 float4), fully coalesced.
        const int bb = blockIdx.x - 1024;                      // 0..127
        const float4* Hv = (const float4*)H + bb * 4096;
        float s0 = 0.f, s1 = 0.f, s2 = 0.f, s3 = 0.f;
        float q0 = 0.f, q1 = 0.f, q2 = 0.f, q3 = 0.f;
#pragma unroll 4
        for (int s = 0; s < 16; ++s) {
            float4 v = Hv[s * 256 + t];
            s0 += v.x; q0 += v.x * v.x;
            s1 += v.y; q1 += v.y * v.y;
            s2 += v.z; q2 += v.z * v.z;
            s3 += v.w; q3 += v.w * v.w;
        }
        float* part = (float*)smem4;                           // [256][8]
        part[t * 8 + 0] = s0; part[t * 8 + 1] = s1;
        part[t * 8 + 2] = s2; part[t * 8 + 3] = s3;
        part[t * 8 + 4] = q0; part[t * 8 + 5] = q1;
        part[t * 8 + 6] = q2; part[t * 8 + 7] = q3;
        __syncthreads();
        if (t < 64) {
            const int g = t >> 2, e = t & 3;   // contributors: threads g+16k
            float a = 0.f, a2 = 0.f;
#pragma unroll
            for (int k = 0; k < 16; ++k) {
                a  += part[(g + 16 * k) * 8 + e];
                a2 += part[(g + 16 * k) * 8 + 4 + e];
            }
            ws[PART_OFF + bb * 64 + t] = a;
            ws[PART_OFF + 128 * 64 + bb * 64 + t] = a2;
        }
    }
}

// ---- Kernel 2: X = Hn@W + b via MFMA with BN folded into W' ------------------
// (h*sc+sh)@W + b  ==  H@(diag(sc)W) + (b + sh^T W).  Per block: 64 rows.
__global__ __launch_bounds__(256) void linear_xy(
    const float* __restrict__ H, const float* __restrict__ Wm,
    const float* __restrict__ bias, const float* __restrict__ gamma,
    const float* __restrict__ beta, const float* __restrict__ ws,
    float* __restrict__ X, unsigned short* __restrict__ Yt) {
    __shared__ float Hl[64 * 64];              // 16 KB fp32 (swizzled content)
    __shared__ float Wl[64 * 64];              // 16 KB raw W
    __shared__ unsigned short Wbf[64 * 64];    // 8 KB  W' bf16 [o][c] swizzled
    __shared__ unsigned short ytile[64][66];
    __shared__ float ls[256], ls2[256];
    __shared__ float sscale[64], sshift[64], bp[64], sdl[64];
    const int b = blockIdx.x >> 4, ch = blockIdx.x & 15;
    const int r0g = b * NL + ch * 64;
    const int t = threadIdx.x, lane = t & 63, w = t >> 6;

    // 1. async H staging: 64 rows x 256B, source-side inverse swizzle (rule 21)
    {
        const char* hsrc = (const char*)H + (size_t)r0g * 256;
#pragma unroll
        for (int i = 0; i < 4; ++i) {
            const int L = i * 4096 + t * 16;
            const int row = L >> 8, cb = L & 255;
            gload16(hsrc + (size_t)row * 256 + (cb ^ ((row & 7) << 4)),
                    (char*)Hl + L);
        }
    }
    // 2. W load + sdl preload + BN partial reduce (overlap H latency)
    {
        const float4* Wv = (const float4*)Wm;
        float4* Wd = (float4*)Wl;
#pragma unroll
        for (int k = 0; k < 4; ++k) Wd[t + k * 256] = Wv[t + k * 256];
    }
    if (t < 64) sdl[t] = rsqrtf(ws[D_OFF + r0g + t]);
    {
        const float* ps  = ws + PART_OFF;
        const float* ps2 = ws + PART_OFF + 128 * 64;
        const int c = t & 63, q = t >> 6;
        float s = 0.f, s2 = 0.f;
        for (int p = q * 32; p < q * 32 + 32; ++p) {
            s  += ps[p * 64 + c];
            s2 += ps2[p * 64 + c];
        }
        ls[t] = s; ls2[t] = s2;
    }
    __syncthreads();
    if (t < 64) {
        const int c = t;
        float T  = ls[c]  + ls[c + 64]  + ls[c + 128]  + ls[c + 192];
        float T2 = ls2[c] + ls2[c + 64] + ls2[c + 128] + ls2[c + 192];
        const float n = (float)(NB * NL);
        float mean = T / n;
        float var  = T2 / n - mean * mean;
        float sc = gamma[c] * rsqrtf(var + BN_EPS);
        sscale[c] = sc;
        sshift[c] = beta[c] - mean * sc;
    }
    __syncthreads();
    // 3. b' partials = sum_c sh_c * W[c][o]   (o = lane, c-range per wave)
    {
        float p = 0.f;
#pragma unroll
        for (int c0 = 0; c0 < 16; ++c0) {
            const int c = w * 16 + c0;
            p += sshift[c] * Wl[c * 64 + lane];
        }
        ls[t] = p;
    }
    // 4. W' bf16 [o][c] swizzled: Wbf[o][c] = bf16(sc_c * W[c][o])
#pragma unroll
    for (int c0 = 0; c0 < 16; ++c0) {
        const int c = w * 16 + c0;
        const float v = sscale[c] * Wl[c * 64 + lane];
        *(unsigned short*)((char*)Wbf + ((lane * 128 + c * 2) ^ ((lane & 7) << 4)))
            = f2bf(v);
    }
    __syncthreads();                 // ls ready, Wbf ready, vmcnt drained (Hl ok)
    if (t < 64) bp[t] = bias[t] + ls[t] + ls[t + 64] + ls[t + 128] + ls[t + 192];
    __syncthreads();

    // 5. MFMA: 4 waves, each a 32x32 quadrant of the 64x64 output
    const int wr0  = (w >> 1) * 32;
    const int wc0  = (w & 1) * 32;
    const int frow = wr0 + (lane & 31);
    const int fcol = wc0 + (lane & 31);
    const int khb  = (lane >> 5) * 16;
    const int kfh  = (lane >> 5) * 32;
    const int swA  = (frow & 7) << 4;
    const int swY  = (fcol & 7) << 4;
    f32x16 acc;
#pragma unroll
    for (int r = 0; r < 16; ++r) acc[r] = 0.f;
    const char* ab = (const char*)Hl;
    const char* wb = (const char*)Wbf;
#pragma unroll
    for (int ks = 0; ks < 4; ++ks) {
        const int b0 = frow * 256 + ks * 64 + kfh;
        f32x4 flo = *(const f32x4*)(ab + ((b0)      ^ swA));
        f32x4 fhi = *(const f32x4*)(ab + ((b0 + 16) ^ swA));
        s16x8 af = cvt8(flo, fhi);
        s16x8 bf = *(const s16x8*)(wb + ((fcol * 128 + ks * 32 + khb) ^ swY));
        acc = __builtin_amdgcn_mfma_f32_32x32x16_bf16(af, bf, acc, 0, 0, 0);
    }
    // 6. epilogue: X = acc + b'; ytile = bf16(X * rsqrt(d))
#pragma unroll
    for (int reg = 0; reg < 16; ++reg) {
        const int row = wr0 + (reg & 3) + 8 * (reg >> 2) + 4 * (lane >> 5);
        const int col = wc0 + (lane & 31);
        const float x = acc[reg] + bp[col];
        X[(size_t)(r0g + row) * NO + col] = x;
        ytile[row][col] = f2bf(x * sdl[row]);
    }
    __syncthreads();
    // 7. coalesced swizzled Yt tile write (unchanged)
    char* ybase = (char*)Yt + (size_t)(b * 16 + ch) * 8192;
#pragma unroll
    for (int i2 = 0; i2 < 16; ++i2) {
        const int col = i2 * 4 + w;
        *(unsigned short*)(ybase + ((col * 128 + lane * 2) ^ ((col & 7) << 4))) =
            ytile[lane][col];
    }
}

// ---- Kernel 3: out = leaky(X - sqrt(d_i) * (A @ Y))  [MFMA, fp32 A staging] --
__global__ __launch_bounds__(256) void prop_mfma(
    const float* __restrict__ A, const unsigned short* __restrict__ Yt,
    const float* __restrict__ dbuf, float* __restrict__ XO) {

    __shared__ float Abuf[2][64 * 64];             // 2 x 16 KB fp32 (swizzled)
    __shared__ unsigned short Ybuf[2][64 * 64];    // 2 x 8 KB bf16 (pre-swizzled)
    __shared__ float sdl[64];

    const int b  = blockIdx.x >> 4;
    const int mt = blockIdx.x & 15;
    const int i0 = mt * 64;
    const char* Abase = (const char*)A + ((size_t)(b * NL + i0)) * 4096;
    const char* YbT   = (const char*)Yt + (size_t)b * 16 * 8192;

    const int t    = threadIdx.x;
    const int lane = t & 63;
    const int w    = t >> 6;

    if (t < 64) sdl[t] = sqrtf(dbuf[b * NL + i0 + t]);

    const int tr = t >> 4;               // 0..15
    const int tc = (t & 15) * 16;        // byte col 0..240
    const char* As[4];
#pragma unroll
    for (int i = 0; i < 4; ++i) {
        const int row = i * 16 + tr;     // 0..63
        As[i] = Abase + (size_t)row * 4096 + (tc ^ ((row & 7) << 4));
    }
    const int yL0 = t * 16, yL1 = t * 16 + 4096;

    const int wr0  = (w >> 1) * 32;
    const int wc0  = (w & 1) * 32;
    const int frow = wr0 + (lane & 31);
    const int fcol = wc0 + (lane & 31);
    const int khb  = (lane >> 5) * 16;   // bf16 half-offset in 128B row
    const int kfh  = (lane >> 5) * 32;   // fp32 half-offset in 256B row
    const int swA  = (frow & 7) << 4;
    const int swY  = (fcol & 7) << 4;

    f32x16 acc;
#pragma unroll
    for (int r = 0; r < 16; ++r) acc[r] = 0.f;

#define STAGE(bi, kt) do {                                                     \
        char* ad = (char*)Abuf[bi];                                            \
        gload16(As[0] + (kt) * 256, ad + t * 16);                              \
        gload16(As[1] + (kt) * 256, ad + 4096  + t * 16);                      \
        gload16(As[2] + (kt) * 256, ad + 8192  + t * 16);                      \
        gload16(As[3] + (kt) * 256, ad + 12288 + t * 16);                      \
        const char* ys = YbT + (size_t)(kt) * 8192;                            \
        char* yd = (char*)Ybuf[bi];                                            \
        gload16(ys + yL0, yd + yL0);                                           \
        gload16(ys + yL1, yd + yL1);                                           \
    } while (0)

    STAGE(0, 0);
    __syncthreads();

#pragma unroll 1
    for (int kti = 0; kti < 16; ++kti) {
        const int nxt = kti + 1;
        if (nxt < 16) STAGE(nxt & 1, nxt);      // prefetch next tile (async)
        const char* ab  = (const char*)Abuf[kti & 1];
        const char* yb2 = (const char*)Ybuf[kti & 1];
#pragma unroll
        for (int ks = 0; ks < 4; ++ks) {
            const int b0 = frow * 256 + ks * 64 + kfh;
            f32x4 flo = *(const f32x4*)(ab + ((b0)      ^ swA));
            f32x4 fhi = *(const f32x4*)(ab + ((b0 + 16) ^ swA));
            s16x8 af = cvt8(flo, fhi);
            s16x8 bf = *(const s16x8*)(yb2 + ((fcol * 128 + ks * 32 + khb) ^ swY));
            acc = __builtin_amdgcn_mfma_f32_32x32x16_bf16(af, bf, acc, 0, 0, 0);
        }
        __syncthreads();                        // drains vmcnt: next tile resident
    }
#undef STAGE

    // epilogue: out = leaky(X - sqrt(d_i) * acc)
#pragma unroll
    for (int reg = 0; reg < 16; ++reg) {
        int row = (reg & 3) + 8 * (reg >> 2) + 4 * (lane >> 5);
        int i   = i0 + wr0 + row;
        int col = wc0 + (lane & 31);
        size_t idx = ((size_t)(b * NL + i)) * NO + col;
        float x = XO[idx];
        float v = x - sdl[wr0 + row] * acc[reg];
        XO[idx] = v > 0.f ? v : 0.01f * v;
    }
}

extern "C" void kernel_launch(void* const* d_in, const int* in_sizes, int n_in,
                              void* d_out, int out_size, void* d_ws, size_t ws_size,
                              hipStream_t stream) {
    const float* H     = (const float*)d_in[0];
    const float* A     = (const float*)d_in[1];
    const float* gamma = (const float*)d_in[2];
    const float* beta  = (const float*)d_in[3];
    const float* Wm    = (const float*)d_in[4];
    const float* bias  = (const float*)d_in[5];
    float* out = (float*)d_out;
    float* ws  = (float*)d_ws;
    unsigned short* Yt = (unsigned short*)(ws + YT_OFF);

    deg_bn<<<1152, 256, 0, stream>>>(A, H, ws);
    linear_xy<<<512, 256, 0, stream>>>(H, Wm, bias, gamma, beta, ws, out, Yt);
    prop_mfma<<<512, 256, 0, stream>>>(A, Yt, ws + D_OFF, out);
}